// Round 17
// baseline (1963.442 us; speedup 1.0000x reference)
//
#include <hip/hip_runtime.h>

#define NI 8
#define NH 64
#define NO 8
#define NB 256
#define NT 2048

typedef float v2f __attribute__((ext_vector_type(2)));

__device__ __forceinline__ v2f fma2(v2f a, v2f b, v2f c) {
    return __builtin_elementwise_fma(a, b, c);
}

// tanh(s) = 1 - 2/(exp(2s)+1); safe at +-inf
__device__ __forceinline__ float tanh_fast(float s) {
    float e = __expf(2.0f * s);
    return fmaf(-2.0f, __builtin_amdgcn_rcpf(e + 1.0f), 1.0f);
}

// SINGLE WAVE per batch element — the conveyor killer.
// R16 proved per-wave period scales ~1:1 with per-wave work (no free stall),
// and R11/R15 showed ~300cyc/step of the 858 period was inter-wave coupling
// (flags, polls, jitter). A single wave pays zero coupling. It's possible now
// because amdgpu_waves_per_eu(1,1) raises the VGPR budget to 512 (R10: 52->132
// proved the attribute works; m08: no spill through 450), so all four weight
// matrices (264 regs) live in one wave's registers.
// Per step t: gather h0[t-1],h1[t-2] (32 b128 bcast); dots Whh0,Wih1->pi[t-1],
// Whh1, Wfc (128 pk_fma); x-dot folded into Whh0 accs; h0[t],h1[t-1]=tanh;
// FC(t-2) store (complete dot per lane, no reduction); 2 LDS writes.
__attribute__((amdgpu_waves_per_eu(1, 1)))
__global__ void __launch_bounds__(64) rnn_solo(
    const float* __restrict__ x,
    const float* __restrict__ W_ih0, const float* __restrict__ W_hh0,
    const float* __restrict__ b_ih0, const float* __restrict__ b_hh0,
    const float* __restrict__ W_ih1, const float* __restrict__ W_hh1,
    const float* __restrict__ b_ih1, const float* __restrict__ b_hh1,
    const float* __restrict__ W_fc,  const float* __restrict__ b_fc,
    float* __restrict__ out)
{
    const int b    = blockIdx.x;
    const int lane = threadIdx.x;
    const int o    = lane & 7;

    __shared__ __align__(16) float xs[2][64][NI];   // x chunks (double-buffered)
    __shared__ __align__(16) float h0s[NH];
    __shared__ __align__(16) float h1s[NH];

    // ---- all four weight matrices in registers (264 VGPRs, budget 512) ----
    v2f wh[NH / 2], wi[NH / 2], wh1[NH / 2], wf[NH / 2];
    #pragma unroll
    for (int k = 0; k < NH / 2; ++k) {
        wh[k]  = v2f{W_hh0[lane * NH + 2 * k], W_hh0[lane * NH + 2 * k + 1]};
        wi[k]  = v2f{W_ih1[lane * NH + 2 * k], W_ih1[lane * NH + 2 * k + 1]};
        wh1[k] = v2f{W_hh1[lane * NH + 2 * k], W_hh1[lane * NH + 2 * k + 1]};
        wf[k]  = v2f{W_fc[o * NH + 2 * k],     W_fc[o * NH + 2 * k + 1]};
    }
    #pragma unroll
    for (int k = 0; k < NH / 2; ++k) {
        asm("" : "+v"(wh[k]));  asm("" : "+v"(wi[k]));
        asm("" : "+v"(wh1[k])); asm("" : "+v"(wf[k]));
    }
    v2f wx[NI / 2];
    #pragma unroll
    for (int m = 0; m < NI / 2; ++m)
        wx[m] = v2f{W_ih0[lane * NI + 2 * m], W_ih0[lane * NI + 2 * m + 1]};

    const float bias0 = b_ih0[lane] + b_hh0[lane];
    const float bias1 = b_ih1[lane] + b_hh1[lane];
    const float bfc   = b_fc[o];

    const float* xb   = x   + (size_t)b * NT * NI;
    float*       outb = out + (size_t)b * NT * NO;
    const size_t hid  = (size_t)NB * NT * NO;

    // init state + stage x chunk 0 (same-wave write->read ordering)
    h0s[lane] = 0.0f;
    h1s[lane] = 0.0f;
    {
        float4 q0 = *(const float4*)(xb + (size_t)lane * NI);
        float4 q1 = *(const float4*)(xb + (size_t)lane * NI + 4);
        *(float4*)(&xs[0][lane][0]) = q0;
        *(float4*)(&xs[0][lane][4]) = q1;
    }
    float4 xn0 = {0, 0, 0, 0}, xn1 = {0, 0, 0, 0};
    float h0n = 0.0f, h1n = 0.0f;

    for (int t = 0; t < NT; ++t) {
        const int m  = t & 63;
        const int cb = (t >> 6) & 1;
        if (m == 0) {                            // issue next-chunk loads (~64 steps early)
            const int c = (t >> 6) + 1;
            if (c < NT / 64) {
                xn0 = *(const float4*)(xb + (size_t)(c * 64 + lane) * NI);
                xn1 = *(const float4*)(xb + (size_t)(c * 64 + lane) * NI + 4);
            }
        }

        // ---- gathers: h0[t-1], h1[t-2], x[t] (broadcast b128, one drain) ----
        const float4* g0 = (const float4*)h0s;
        const float4* g1 = (const float4*)h1s;
        const float4  xv0 = ((const float4*)&xs[cb][m][0])[0];
        const float4  xv1 = ((const float4*)&xs[cb][m][0])[1];

        // ---- 4 dots, 16 independent accumulator chains ----
        v2f aW0 = {bias0, 0.f}, aW1 = {0,0}, aW2 = {0,0}, aW3 = {0,0};   // Whh0 (+x+b0)
        v2f aI0 = {0,0}, aI1 = {0,0}, aI2 = {0,0}, aI3 = {0,0};          // Wih1 -> pi[t-1]
        v2f aH0 = {bias1, 0.f}, aH1 = {0,0}, aH2 = {0,0}, aH3 = {0,0};   // Whh1 (+b1)
        v2f aF0 = {0,0}, aF1 = {0,0}, aF2 = {0,0}, aF3 = {0,0};          // Wfc
        #pragma unroll
        for (int k = 0; k < 16; ++k) {
            const float4 q0 = g0[k];
            const float4 q1 = g1[k];
            const v2f l0 = {q0.x, q0.y}, u0 = {q0.z, q0.w};
            const v2f l1 = {q1.x, q1.y}, u1 = {q1.z, q1.w};
            if (k & 1) {
                aW2 = fma2(l0, wh[2*k],  aW2); aW3 = fma2(u0, wh[2*k+1],  aW3);
                aI2 = fma2(l0, wi[2*k],  aI2); aI3 = fma2(u0, wi[2*k+1],  aI3);
                aH2 = fma2(l1, wh1[2*k], aH2); aH3 = fma2(u1, wh1[2*k+1], aH3);
                aF2 = fma2(l1, wf[2*k],  aF2); aF3 = fma2(u1, wf[2*k+1],  aF3);
            } else {
                aW0 = fma2(l0, wh[2*k],  aW0); aW1 = fma2(u0, wh[2*k+1],  aW1);
                aI0 = fma2(l0, wi[2*k],  aI0); aI1 = fma2(u0, wi[2*k+1],  aI1);
                aH0 = fma2(l1, wh1[2*k], aH0); aH1 = fma2(u1, wh1[2*k+1], aH1);
                aF0 = fma2(l1, wf[2*k],  aF0); aF1 = fma2(u1, wf[2*k+1],  aF1);
            }
        }
        // fold x[t] dot into the Whh0 chains
        aW0 = fma2(v2f{xv0.x, xv0.y}, wx[0], aW0);
        aW1 = fma2(v2f{xv0.z, xv0.w}, wx[1], aW1);
        aW2 = fma2(v2f{xv1.x, xv1.y}, wx[2], aW2);
        aW3 = fma2(v2f{xv1.z, xv1.w}, wx[3], aW3);

        const v2f sW = (aW0 + aW1) + (aW2 + aW3);
        const v2f sI = (aI0 + aI1) + (aI2 + aI3);
        const v2f sH = (aH0 + aH1) + (aH2 + aH3);
        const v2f sF = (aF0 + aF1) + (aF2 + aF3);

        // FC(t-2) from h1[t-2] gather (complete dot per lane, no reduction)
        if (t >= 2 && lane < NO)
            outb[(size_t)(t - 2) * NO + o] = sF.x + sF.y + bfc;   // fire-and-forget

        const float h1new = tanh_fast((sH.x + sH.y) + (sI.x + sI.y));
        h1n = (t == 0) ? 0.0f : h1new;           // h1[t-1] (h1[-1] = 0)
        h0n = tanh_fast(sW.x + sW.y);            // h0[t]

        h0s[lane] = h0n;
        h1s[lane] = h1n;

        if (m == 32) {                           // stage next chunk into other buffer
            const int c = (t >> 6) + 1;
            if (c < NT / 64) {
                *(float4*)(&xs[cb ^ 1][lane][0]) = xn0;
                *(float4*)(&xs[cb ^ 1][lane][4]) = xn1;
            }
        }
    }

    // ---- epilogue: h1[NT-1], FC(NT-2), FC(NT-1), hidden state ----
    {
        const float4* g0 = (const float4*)h0s;   // h0[NT-1]
        const float4* g1 = (const float4*)h1s;   // h1[NT-2]
        v2f aI0 = {0,0}, aI1 = {0,0}, aI2 = {0,0}, aI3 = {0,0};
        v2f aH0 = {bias1, 0.f}, aH1 = {0,0}, aH2 = {0,0}, aH3 = {0,0};
        v2f aF0 = {0,0}, aF1 = {0,0}, aF2 = {0,0}, aF3 = {0,0};
        #pragma unroll
        for (int k = 0; k < 16; ++k) {
            const float4 q0 = g0[k];
            const float4 q1 = g1[k];
            const v2f l0 = {q0.x, q0.y}, u0 = {q0.z, q0.w};
            const v2f l1 = {q1.x, q1.y}, u1 = {q1.z, q1.w};
            if (k & 1) {
                aI2 = fma2(l0, wi[2*k],  aI2); aI3 = fma2(u0, wi[2*k+1],  aI3);
                aH2 = fma2(l1, wh1[2*k], aH2); aH3 = fma2(u1, wh1[2*k+1], aH3);
                aF2 = fma2(l1, wf[2*k],  aF2); aF3 = fma2(u1, wf[2*k+1],  aF3);
            } else {
                aI0 = fma2(l0, wi[2*k],  aI0); aI1 = fma2(u0, wi[2*k+1],  aI1);
                aH0 = fma2(l1, wh1[2*k], aH0); aH1 = fma2(u1, wh1[2*k+1], aH1);
                aF0 = fma2(l1, wf[2*k],  aF0); aF1 = fma2(u1, wf[2*k+1],  aF1);
            }
        }
        const v2f sI = (aI0 + aI1) + (aI2 + aI3);
        const v2f sH = (aH0 + aH1) + (aH2 + aH3);
        const v2f sF = (aF0 + aF1) + (aF2 + aF3);
        if (lane < NO)
            outb[(size_t)(NT - 2) * NO + o] = sF.x + sF.y + bfc;   // FC(NT-2)
        h1n = tanh_fast((sH.x + sH.y) + (sI.x + sI.y));            // h1[NT-1]
        h1s[lane] = h1n;
    }
    {
        const float4* g1 = (const float4*)h1s;   // h1[NT-1]
        v2f aF0 = {0,0}, aF1 = {0,0}, aF2 = {0,0}, aF3 = {0,0};
        #pragma unroll
        for (int k = 0; k < 16; ++k) {
            const float4 q1 = g1[k];
            const v2f l1 = {q1.x, q1.y}, u1 = {q1.z, q1.w};
            if (k & 1) { aF2 = fma2(l1, wf[2*k], aF2); aF3 = fma2(u1, wf[2*k+1], aF3); }
            else       { aF0 = fma2(l1, wf[2*k], aF0); aF1 = fma2(u1, wf[2*k+1], aF1); }
        }
        const v2f sF = (aF0 + aF1) + (aF2 + aF3);
        if (lane < NO)
            outb[(size_t)(NT - 1) * NO + o] = sF.x + sF.y + bfc;   // FC(NT-1)
    }
    out[hid + (size_t)b * NH + lane]                     = h0n;    // h0 final
    out[hid + (size_t)NB * NH + (size_t)b * NH + lane]   = h1n;    // h1 final
}

extern "C" void kernel_launch(void* const* d_in, const int* in_sizes, int n_in,
                              void* d_out, int out_size, void* d_ws, size_t ws_size,
                              hipStream_t stream) {
    const float* x     = (const float*)d_in[0];
    const float* W_ih0 = (const float*)d_in[1];
    const float* W_hh0 = (const float*)d_in[2];
    const float* b_ih0 = (const float*)d_in[3];
    const float* b_hh0 = (const float*)d_in[4];
    const float* W_ih1 = (const float*)d_in[5];
    const float* W_hh1 = (const float*)d_in[6];
    const float* b_ih1 = (const float*)d_in[7];
    const float* b_hh1 = (const float*)d_in[8];
    const float* W_fc  = (const float*)d_in[9];
    const float* b_fc  = (const float*)d_in[10];

    rnn_solo<<<dim3(NB), dim3(64), 0, stream>>>(
        x, W_ih0, W_hh0, b_ih0, b_hh0,
        W_ih1, W_hh1, b_ih1, b_hh1, W_fc, b_fc,
        (float*)d_out);
}

// Round 18
// 787.102 us; speedup vs baseline: 2.4945x; 2.4945x over previous
//
#include <hip/hip_runtime.h>

#define NI 8
#define NH 64
#define NO 8
#define NB 256
#define NT 2048

typedef float v2f __attribute__((ext_vector_type(2)));

__device__ __forceinline__ v2f fma2(v2f a, v2f b, v2f c) {
    return __builtin_elementwise_fma(a, b, c);
}

// tanh(s) = 1 - 2/(exp(2s)+1); safe at +-inf
__device__ __forceinline__ float tanh_fast(float s) {
    float e = __expf(2.0f * s);
    return fmaf(-2.0f, __builtin_amdgcn_rcpf(e + 1.0f), 1.0f);
}

// TWO waves, ONE hop. R15's conveyor (best: 709us) minus wave D: the x-dot
// (8 fmas) folds into A directly; A self-stages x chunks (loads at m==0,
// LDS-write at m==32, double-buffered). R16/R17 bracketed the topology space:
// fewer waves = un-hideable serial latency, more waves = per-hop tax
// (~150cyc/hop: publish lgkmcnt + flag + poll quantization + jitter).
//   A: h0[t] = tanh(Whh0@h0[t-1] + Wih0@x[t] + b0); same gather -> pi[t-1]
//   C: h1[t] = tanh(pi[t] + b1 + Whh1@h1[t-1]); same gather -> FC(t-1)/lane
// Protocol byte-copied from R15 (proven): pir 32-ring, deferred pi write,
// A publishes vfa=t-2 at odd t; C polls gran-4 (covers +1 prefetch),
// publishes vfc2 gran-4; A polls vfc2>=t-27 gran-8.
__attribute__((amdgpu_waves_per_eu(1, 1)))
__global__ void __launch_bounds__(128) rnn_duo2(
    const float* __restrict__ x,
    const float* __restrict__ W_ih0, const float* __restrict__ W_hh0,
    const float* __restrict__ b_ih0, const float* __restrict__ b_hh0,
    const float* __restrict__ W_ih1, const float* __restrict__ W_hh1,
    const float* __restrict__ b_ih1, const float* __restrict__ b_hh1,
    const float* __restrict__ W_fc,  const float* __restrict__ b_fc,
    float* __restrict__ out)
{
    const int b    = blockIdx.x;
    const int tid  = threadIdx.x;
    const int wid  = tid >> 6;
    const int lane = tid & 63;
    const int o    = lane & 7;

    __shared__ __align__(16) float xs[2][64][NI];   // A-private x chunks
    __shared__ __align__(16) float pir[32][NH];     // A -> C ring
    __shared__ __align__(16) float h0s[NH];         // A-private gather buffer
    __shared__ __align__(16) float h1s[NH];         // C-private gather buffer
    __shared__ int fa, fc2;

    if (tid == 0) { fa = -1; fc2 = -1; }
    __syncthreads();

    volatile int* vfa  = &fa;
    volatile int* vfc2 = &fc2;

    const float*  xb   = x   + (size_t)b * NT * NI;
    float*        outb = out + (size_t)b * NT * NO;
    const size_t  hid  = (size_t)NB * NT * NO;

    if (wid == 0) {
        // ========== wave A: h0 chain + x-dot + pi production ==========
        v2f wh[NH / 2], wi[NH / 2], wx[NI / 2];
        #pragma unroll
        for (int k = 0; k < NH / 2; ++k) {
            wh[k] = v2f{W_hh0[lane * NH + 2 * k], W_hh0[lane * NH + 2 * k + 1]};
            wi[k] = v2f{W_ih1[lane * NH + 2 * k], W_ih1[lane * NH + 2 * k + 1]};
        }
        #pragma unroll
        for (int m = 0; m < NI / 2; ++m)
            wx[m] = v2f{W_ih0[lane * NI + 2 * m], W_ih0[lane * NI + 2 * m + 1]};
        #pragma unroll
        for (int k = 0; k < NH / 2; ++k) { asm("" : "+v"(wh[k])); asm("" : "+v"(wi[k])); }
        const float bias0 = b_ih0[lane] + b_hh0[lane];

        // stage x chunk 0 (same-wave write->read ordering)
        {
            float4 q0 = *(const float4*)(xb + (size_t)lane * NI);
            float4 q1 = *(const float4*)(xb + (size_t)lane * NI + 4);
            *(float4*)(&xs[0][lane][0]) = q0;
            *(float4*)(&xs[0][lane][4]) = q1;
        }
        float4 xn0 = {0, 0, 0, 0}, xn1 = {0, 0, 0, 0};
        float h0n = 0.0f, dI_prev = 0.0f;

        for (int t = 0; t < NT; ++t) {
            const int m  = t & 63;
            const int cb = (t >> 6) & 1;
            if (m == 0) {                        // issue next-chunk loads (32 steps early)
                const int c = (t >> 6) + 1;
                if (c < NT / 64) {
                    xn0 = *(const float4*)(xb + (size_t)(c * 64 + lane) * NI);
                    xn1 = *(const float4*)(xb + (size_t)(c * 64 + lane) * NI + 4);
                }
            }
            if ((t & 7) == 0) {                  // pir slot reuse vs C (32-ring)
                while (*vfc2 < t - 27) {}
                asm volatile("" ::: "memory");
            }
            h0s[lane] = h0n;                     // h0[t-1]
            const float4* hp = (const float4*)h0s;
            const float4  xv0 = ((const float4*)&xs[cb][m][0])[0];
            const float4  xv1 = ((const float4*)&xs[cb][m][0])[1];
            if (t >= 2) pir[(t - 2) & 31][lane] = dI_prev;   // deferred pi write

            v2f aW0 = {bias0, 0.f}, aW1 = {0,0}, aW2 = {0,0}, aW3 = {0,0};
            v2f aI0 = {0,0}, aI1 = {0,0}, aI2 = {0,0}, aI3 = {0,0};
            #pragma unroll
            for (int k = 0; k < 16; ++k) {
                const float4 g = hp[k];
                const v2f lo = {g.x, g.y}, hi = {g.z, g.w};
                if (k & 1) {
                    aW2 = fma2(lo, wh[2*k], aW2); aW3 = fma2(hi, wh[2*k+1], aW3);
                    aI2 = fma2(lo, wi[2*k], aI2); aI3 = fma2(hi, wi[2*k+1], aI3);
                } else {
                    aW0 = fma2(lo, wh[2*k], aW0); aW1 = fma2(hi, wh[2*k+1], aW1);
                    aI0 = fma2(lo, wi[2*k], aI0); aI1 = fma2(hi, wi[2*k+1], aI1);
                }
            }
            aW0 = fma2(v2f{xv0.x, xv0.y}, wx[0], aW0);       // fold x[t] dot
            aW1 = fma2(v2f{xv0.z, xv0.w}, wx[1], aW1);
            aW2 = fma2(v2f{xv1.x, xv1.y}, wx[2], aW2);
            aW3 = fma2(v2f{xv1.z, xv1.w}, wx[3], aW3);

            if (t & 1) {                         // publish: all DS ops returned
                asm volatile("s_waitcnt lgkmcnt(0)" ::: "memory");
                *vfa = t - 2;
            }
            const v2f sW = (aW0 + aW1) + (aW2 + aW3);
            const v2f sI = (aI0 + aI1) + (aI2 + aI3);
            dI_prev = sI.x + sI.y;               // pi[t-1], written next step
            h0n = tanh_fast(sW.x + sW.y);        // h0[t]

            if (m == 32) {                       // stage prefetched chunk
                const int c = (t >> 6) + 1;
                if (c < NT / 64) {
                    *(float4*)(&xs[cb ^ 1][lane][0]) = xn0;
                    *(float4*)(&xs[cb ^ 1][lane][4]) = xn1;
                }
            }
        }

        // epilogue: pi[NT-2] (pending) and pi[NT-1] (fresh gather)
        while (*vfc2 < NT - 29) {}
        asm volatile("" ::: "memory");
        pir[(NT - 2) & 31][lane] = dI_prev;
        h0s[lane] = h0n;
        {
            const float4* hp = (const float4*)h0s;
            v2f aI0 = {0,0}, aI1 = {0,0}, aI2 = {0,0}, aI3 = {0,0};
            #pragma unroll
            for (int k = 0; k < 16; ++k) {
                const float4 g = hp[k];
                const v2f lo = {g.x, g.y}, hi = {g.z, g.w};
                if (k & 1) { aI2 = fma2(lo, wi[2*k], aI2); aI3 = fma2(hi, wi[2*k+1], aI3); }
                else       { aI0 = fma2(lo, wi[2*k], aI0); aI1 = fma2(hi, wi[2*k+1], aI1); }
            }
            const v2f sI = (aI0 + aI1) + (aI2 + aI3);
            pir[(NT - 1) & 31][lane] = sI.x + sI.y;
        }
        asm volatile("s_waitcnt lgkmcnt(0)" ::: "memory");
        *vfa = NT - 1;
        out[hid + (size_t)b * NH + lane] = h0n;                     // h0 final
    } else {
        // ========== wave C: h1 chain + FC ==========
        v2f wh1[NH / 2], wf[NH / 2];
        #pragma unroll
        for (int k = 0; k < NH / 2; ++k) {
            wh1[k] = v2f{W_hh1[lane * NH + 2 * k], W_hh1[lane * NH + 2 * k + 1]};
            wf[k]  = v2f{W_fc[o * NH + 2 * k],     W_fc[o * NH + 2 * k + 1]};
        }
        #pragma unroll
        for (int k = 0; k < NH / 2; ++k) { asm("" : "+v"(wh1[k])); asm("" : "+v"(wf[k])); }
        const float bias1 = b_ih1[lane] + b_hh1[lane];
        const float bfc   = b_fc[o];
        float h1n = 0.0f;

        while (*vfa < 0) {}                      // pi[0] available
        asm volatile("" ::: "memory");
        float pv_next = pir[0][lane];

        for (int t = 0; t < NT; ++t) {
            if ((t & 3) == 0) {                  // covers prefetch through t+4
                const int need = (t + 4 < NT) ? t + 4 : NT - 1;
                while (*vfa < need) {}
                asm volatile("" ::: "memory");
            }
            const float pv_cur = pv_next;
            pv_next = pir[(t + 1) & 31][lane];   // prefetch pi[t+1]

            h1s[lane] = h1n;                     // h1[t-1]
            const float4* hp = (const float4*)h1s;
            v2f aH0 = {bias1, 0.f}, aH1 = {0,0}, aH2 = {0,0}, aH3 = {0,0};
            v2f aF0 = {0,0}, aF1 = {0,0}, aF2 = {0,0}, aF3 = {0,0};
            #pragma unroll
            for (int k = 0; k < 16; ++k) {
                const float4 g = hp[k];
                const v2f lo = {g.x, g.y}, hi = {g.z, g.w};
                if (k & 1) {
                    aH2 = fma2(lo, wh1[2*k], aH2); aH3 = fma2(hi, wh1[2*k+1], aH3);
                    aF2 = fma2(lo, wf[2*k],  aF2); aF3 = fma2(hi, wf[2*k+1],  aF3);
                } else {
                    aH0 = fma2(lo, wh1[2*k], aH0); aH1 = fma2(hi, wh1[2*k+1], aH1);
                    aF0 = fma2(lo, wf[2*k],  aF0); aF1 = fma2(hi, wf[2*k+1],  aF1);
                }
            }
            const v2f sH = (aH0 + aH1) + (aH2 + aH3);
            const v2f sF = (aF0 + aF1) + (aF2 + aF3);

            if (t > 0 && lane < NO)              // FC(t-1), complete dot per lane
                outb[(size_t)(t - 1) * NO + o] = sF.x + sF.y + bfc;

            h1n = tanh_fast(sH.x + sH.y + pv_cur);   // h1[t]
            if ((t & 3) == 3) {                  // consumption progress
                asm volatile("s_waitcnt lgkmcnt(0)" ::: "memory");
                *vfc2 = t;
            }
        }

        // epilogue: FC(NT-1) from h1[NT-1]
        h1s[lane] = h1n;
        {
            const float4* hp = (const float4*)h1s;
            v2f aF0 = {0,0}, aF1 = {0,0}, aF2 = {0,0}, aF3 = {0,0};
            #pragma unroll
            for (int k = 0; k < 16; ++k) {
                const float4 g = hp[k];
                const v2f lo = {g.x, g.y}, hi = {g.z, g.w};
                if (k & 1) { aF2 = fma2(lo, wf[2*k], aF2); aF3 = fma2(hi, wf[2*k+1], aF3); }
                else       { aF0 = fma2(lo, wf[2*k], aF0); aF1 = fma2(hi, wf[2*k+1], aF1); }
            }
            const v2f sF = (aF0 + aF1) + (aF2 + aF3);
            if (lane < NO) outb[(size_t)(NT - 1) * NO + o] = sF.x + sF.y + bfc;
        }
        out[hid + (size_t)NB * NH + (size_t)b * NH + lane] = h1n;   // h1 final
    }
}

extern "C" void kernel_launch(void* const* d_in, const int* in_sizes, int n_in,
                              void* d_out, int out_size, void* d_ws, size_t ws_size,
                              hipStream_t stream) {
    const float* x     = (const float*)d_in[0];
    const float* W_ih0 = (const float*)d_in[1];
    const float* W_hh0 = (const float*)d_in[2];
    const float* b_ih0 = (const float*)d_in[3];
    const float* b_hh0 = (const float*)d_in[4];
    const float* W_ih1 = (const float*)d_in[5];
    const float* W_hh1 = (const float*)d_in[6];
    const float* b_ih1 = (const float*)d_in[7];
    const float* b_hh1 = (const float*)d_in[8];
    const float* W_fc  = (const float*)d_in[9];
    const float* b_fc  = (const float*)d_in[10];

    rnn_duo2<<<dim3(NB), dim3(128), 0, stream>>>(
        x, W_ih0, W_hh0, b_ih0, b_hh0,
        W_ih1, W_hh1, b_ih1, b_hh1, W_fc, b_fc,
        (float*)d_out);
}

// Round 19
// 771.231 us; speedup vs baseline: 2.5459x; 1.0206x over previous
//
#include <hip/hip_runtime.h>

#define NI 8
#define NH 64
#define NO 8
#define NB 256
#define NT 2048

typedef float v2f __attribute__((ext_vector_type(2)));

__device__ __forceinline__ v2f fma2(v2f a, v2f b, v2f c) {
    return __builtin_elementwise_fma(a, b, c);
}

// tanh(s) = 1 - 2/(exp(2s)+1); safe at +-inf
__device__ __forceinline__ float tanh_fast(float s) {
    float e = __expf(2.0f * s);
    return fmaf(-2.0f, __builtin_amdgcn_rcpf(e + 1.0f), 1.0f);
}

// R15 (best: 709us) with ONE change: wave A's body reordered to wave C's
// proven shape — recurrence dot FIRST, tanh, THEN the secondary (Wih1) dot.
// R15's A interleaved both dots before tanh, leaving the ~50cyc exp->rcp
// chain exposed right before the next iteration's state write, on the
// binding stage. C already had this shape; A now matches.
//   A: h0[t]=tanh(Whh0@h0[t-1]+u[t]); then Wih1@h0[t-1] -> pir[t-1]
//   C: h1[t]=tanh(pi[t]+b1+Whh1@h1[t-1]); same gather -> FC(t-1)/lane
//   D: u[t]=Wih0@x[t]+b0, 8-step windows, 2-window lookahead
__attribute__((amdgpu_waves_per_eu(1, 1)))
__global__ void __launch_bounds__(192) rnn_tri5(
    const float* __restrict__ x,
    const float* __restrict__ W_ih0, const float* __restrict__ W_hh0,
    const float* __restrict__ b_ih0, const float* __restrict__ b_hh0,
    const float* __restrict__ W_ih1, const float* __restrict__ W_hh1,
    const float* __restrict__ b_ih1, const float* __restrict__ b_hh1,
    const float* __restrict__ W_fc,  const float* __restrict__ b_fc,
    float* __restrict__ out)
{
    const int b    = blockIdx.x;
    const int tid  = threadIdx.x;
    const int wid  = tid >> 6;
    const int lane = tid & 63;

    __shared__ __align__(16) float ur[32][NH];    // D -> A ring
    __shared__ __align__(16) float pir[32][NH];   // A -> C ring
    __shared__ __align__(16) float h0s[NH];       // A-private gather buffer
    __shared__ __align__(16) float h1s[NH];       // C-private gather buffer
    __shared__ int fa, fc2, fu;

    if (tid == 0) { fa = -1; fc2 = -1; fu = -1; }
    __syncthreads();

    volatile int* vfa  = &fa;
    volatile int* vfc2 = &fc2;
    volatile int* vfu  = &fu;

    const float*  xb   = x   + (size_t)b * NT * NI;
    float*        outb = out + (size_t)b * NT * NO;
    const size_t  hid  = (size_t)NB * NT * NO;

    if (wid == 0) {
        // ========== wave A: h0 chain (recurrence-first order) ==========
        v2f wh[NH / 2], wi[NH / 2];
        #pragma unroll
        for (int k = 0; k < NH / 2; ++k) {
            wh[k] = v2f{W_hh0[lane * NH + 2 * k], W_hh0[lane * NH + 2 * k + 1]};
            wi[k] = v2f{W_ih1[lane * NH + 2 * k], W_ih1[lane * NH + 2 * k + 1]};
        }
        float h0n = 0.0f;

        while (*vfu < 7) {}                      // u[0] ready (D's first window)
        asm volatile("" ::: "memory");
        float uv_next = ur[0][lane];

        for (int t = 0; t < NT; ++t) {
            if ((t & 7) == 0) {
                const int needU = (t + 8 < NT) ? t + 8 : NT - 1;
                while (*vfu < needU) {}          // u availability (covers prefetch)
                while (*vfc2 < t - 27) {}        // pir slot reuse vs C (32-ring)
                asm volatile("" ::: "memory");
            }
            h0s[lane] = h0n;                     // h0[t-1]
            const float4* hp = (const float4*)h0s;
            float4 gv[16];
            #pragma unroll
            for (int k = 0; k < 16; ++k) gv[k] = hp[k];      // issue gather
            const float uv_cur = uv_next;
            uv_next = ur[(t + 1) & 31][lane];                // prefetch u[t+1]

            // ---- recurrence dot FIRST: Whh0 @ h0[t-1] ----
            v2f aW0 = {0,0}, aW1 = {0,0}, aW2 = {0,0}, aW3 = {0,0};
            #pragma unroll
            for (int k = 0; k < 16; ++k) {
                const v2f lo = {gv[k].x, gv[k].y}, hi = {gv[k].z, gv[k].w};
                if (k & 1) { aW2 = fma2(lo, wh[2 * k], aW2); aW3 = fma2(hi, wh[2 * k + 1], aW3); }
                else       { aW0 = fma2(lo, wh[2 * k], aW0); aW1 = fma2(hi, wh[2 * k + 1], aW1); }
            }
            if (t & 1) {                         // publish (drain ~free here)
                asm volatile("s_waitcnt lgkmcnt(0)" ::: "memory");
                *vfa = t - 2;
            }
            const v2f sW = (aW0 + aW1) + (aW2 + aW3);
            h0n = tanh_fast(sW.x + sW.y + uv_cur);           // h0[t]
            __builtin_amdgcn_sched_barrier(0);   // pin: I-dot stays after tanh

            // ---- secondary dot fills tanh latency: Wih1 @ h0[t-1] = pi[t-1] ----
            v2f aI0 = {0,0}, aI1 = {0,0}, aI2 = {0,0}, aI3 = {0,0};
            #pragma unroll
            for (int k = 0; k < 16; ++k) {
                const v2f lo = {gv[k].x, gv[k].y}, hi = {gv[k].z, gv[k].w};
                if (k & 1) { aI2 = fma2(lo, wi[2 * k], aI2); aI3 = fma2(hi, wi[2 * k + 1], aI3); }
                else       { aI0 = fma2(lo, wi[2 * k], aI0); aI1 = fma2(hi, wi[2 * k + 1], aI1); }
            }
            const v2f sI = (aI0 + aI1) + (aI2 + aI3);
            if (t > 0) pir[(t - 1) & 31][lane] = sI.x + sI.y;
        }

        // epilogue: pi[NT-1] from h0[NT-1] (fresh gather)
        while (*vfc2 < NT - 29) {}               // slot reuse (C is >= NT-5 here)
        asm volatile("" ::: "memory");
        h0s[lane] = h0n;
        {
            const float4* hp = (const float4*)h0s;
            v2f aI0 = {0,0}, aI1 = {0,0}, aI2 = {0,0}, aI3 = {0,0};
            #pragma unroll
            for (int k = 0; k < 16; ++k) {
                const float4 g = hp[k];
                const v2f lo = {g.x, g.y}, hi = {g.z, g.w};
                if (k & 1) { aI2 = fma2(lo, wi[2 * k], aI2); aI3 = fma2(hi, wi[2 * k + 1], aI3); }
                else       { aI0 = fma2(lo, wi[2 * k], aI0); aI1 = fma2(hi, wi[2 * k + 1], aI1); }
            }
            const v2f sI = (aI0 + aI1) + (aI2 + aI3);
            pir[(NT - 1) & 31][lane] = sI.x + sI.y;
        }
        asm volatile("s_waitcnt lgkmcnt(0)" ::: "memory");
        *vfa = NT - 1;
        out[hid + (size_t)b * NH + lane] = h0n;                     // h0 final
    } else if (wid == 1) {
        // ========== wave C: h1 chain + FC (byte-identical to R15) ==========
        const int o = lane & 7;
        v2f wh1[NH / 2], wf[NH / 2];
        #pragma unroll
        for (int k = 0; k < NH / 2; ++k) {
            wh1[k] = v2f{W_hh1[lane * NH + 2 * k], W_hh1[lane * NH + 2 * k + 1]};
            wf[k]  = v2f{W_fc[o * NH + 2 * k],     W_fc[o * NH + 2 * k + 1]};
        }
        const float bias1 = b_ih1[lane] + b_hh1[lane];
        const float bfc   = b_fc[o];
        float h1n = 0.0f;

        while (*vfa < 1) {}                      // pi[0] ready
        asm volatile("" ::: "memory");
        float pv_next = pir[0][lane];

        for (int t = 0; t < NT; ++t) {
            if ((t & 3) == 0) {                  // covers prefetch through t+4
                const int need = (t + 4 < NT) ? t + 4 : NT - 1;
                while (*vfa < need) {}
                asm volatile("" ::: "memory");
            }
            h1s[lane] = h1n;                     // h1[t-1]
            const float4* hp = (const float4*)h1s;
            float4 gv[16];
            #pragma unroll
            for (int k = 0; k < 16; ++k) gv[k] = hp[k];
            const float pv_cur = pv_next;
            pv_next = pir[(t + 1) & 31][lane];   // prefetch pi[t+1]

            // on-chain dot first: Whh1 @ h1[t-1]
            v2f aW0 = {0,0}, aW1 = {0,0}, aW2 = {0,0}, aW3 = {0,0};
            #pragma unroll
            for (int k = 0; k < 16; ++k) {
                const v2f lo = {gv[k].x, gv[k].y}, hi = {gv[k].z, gv[k].w};
                if (k & 1) { aW2 = fma2(lo, wh1[2 * k], aW2); aW3 = fma2(hi, wh1[2 * k + 1], aW3); }
                else       { aW0 = fma2(lo, wh1[2 * k], aW0); aW1 = fma2(hi, wh1[2 * k + 1], aW1); }
            }
            const v2f sW = (aW0 + aW1) + (aW2 + aW3);
            h1n = tanh_fast(sW.x + sW.y + pv_cur + bias1);

            // off-chain: FC(t-1) from the same gather (complete dot per lane)
            v2f aF0 = {0,0}, aF1 = {0,0}, aF2 = {0,0}, aF3 = {0,0};
            #pragma unroll
            for (int k = 0; k < 16; ++k) {
                const v2f lo = {gv[k].x, gv[k].y}, hi = {gv[k].z, gv[k].w};
                if (k & 1) { aF2 = fma2(lo, wf[2 * k], aF2); aF3 = fma2(hi, wf[2 * k + 1], aF3); }
                else       { aF0 = fma2(lo, wf[2 * k], aF0); aF1 = fma2(hi, wf[2 * k + 1], aF1); }
            }
            const v2f sF = (aF0 + aF1) + (aF2 + aF3);
            if (t > 0 && lane < NO)
                outb[(size_t)(t - 1) * NO + o] = sF.x + sF.y + bfc;  // fire-and-forget

            if ((t & 3) == 3) {                  // consumption progress
                asm volatile("s_waitcnt lgkmcnt(0)" ::: "memory");
                *vfc2 = t;
            }
        }

        // epilogue: FC(NT-1)
        h1s[lane] = h1n;
        {
            const float4* hp = (const float4*)h1s;
            v2f aF0 = {0,0}, aF1 = {0,0}, aF2 = {0,0}, aF3 = {0,0};
            #pragma unroll
            for (int k = 0; k < 16; ++k) {
                const float4 g = hp[k];
                const v2f lo = {g.x, g.y}, hi = {g.z, g.w};
                if (k & 1) { aF2 = fma2(lo, wf[2 * k], aF2); aF3 = fma2(hi, wf[2 * k + 1], aF3); }
                else       { aF0 = fma2(lo, wf[2 * k], aF0); aF1 = fma2(hi, wf[2 * k + 1], aF1); }
            }
            const v2f sF = (aF0 + aF1) + (aF2 + aF3);
            if (lane < NO) outb[(size_t)(NT - 1) * NO + o] = sF.x + sF.y + bfc;
        }
        out[hid + (size_t)NB * NH + (size_t)b * NH + lane] = h1n;   // h1 final
    } else if (wid == 2) {
        // ========== wave D: u producer (byte-identical to R15) ==========
        float wih0r[NI];
        #pragma unroll
        for (int i = 0; i < NI; ++i) wih0r[i] = W_ih0[lane * NI + i];
        const float bias0 = b_ih0[lane] + b_hh0[lane];

        float4 xc[16], xn[16];                   // xc = window w, xn = window w+1
        #pragma unroll
        for (int j = 0; j < 8; ++j) {
            xc[2 * j]     = *(const float4*)(xb + (size_t)j * NI);
            xc[2 * j + 1] = *(const float4*)(xb + (size_t)j * NI + 4);
        }
        #pragma unroll
        for (int j = 0; j < 8; ++j) {
            xn[2 * j]     = *(const float4*)(xb + (size_t)(8 + j) * NI);
            xn[2 * j + 1] = *(const float4*)(xb + (size_t)(8 + j) * NI + 4);
        }

        for (int w = 0; w < NT / 8; ++w) {
            while (*vfa < 8 * w - 20) {}         // ur slot reuse vs A
            asm volatile("" ::: "memory");
            #pragma unroll
            for (int j = 0; j < 8; ++j) {
                float u = bias0;
                u = fmaf(xc[2 * j].x,     wih0r[0], u);
                u = fmaf(xc[2 * j].y,     wih0r[1], u);
                u = fmaf(xc[2 * j].z,     wih0r[2], u);
                u = fmaf(xc[2 * j].w,     wih0r[3], u);
                u = fmaf(xc[2 * j + 1].x, wih0r[4], u);
                u = fmaf(xc[2 * j + 1].y, wih0r[5], u);
                u = fmaf(xc[2 * j + 1].z, wih0r[6], u);
                u = fmaf(xc[2 * j + 1].w, wih0r[7], u);
                ur[(8 * w + j) & 31][lane] = u;
            }
            asm volatile("s_waitcnt lgkmcnt(0)" ::: "memory");
            *vfu = 8 * w + 7;
            #pragma unroll
            for (int j = 0; j < 16; ++j) xc[j] = xn[j];      // rotate windows
            if (w + 2 < NT / 8) {                // load window w+2
                const size_t base = (size_t)(w + 2) * 8;
                #pragma unroll
                for (int j = 0; j < 8; ++j) {
                    xn[2 * j]     = *(const float4*)(xb + (base + j) * NI);
                    xn[2 * j + 1] = *(const float4*)(xb + (base + j) * NI + 4);
                }
            }
        }
    }
}

extern "C" void kernel_launch(void* const* d_in, const int* in_sizes, int n_in,
                              void* d_out, int out_size, void* d_ws, size_t ws_size,
                              hipStream_t stream) {
    const float* x     = (const float*)d_in[0];
    const float* W_ih0 = (const float*)d_in[1];
    const float* W_hh0 = (const float*)d_in[2];
    const float* b_ih0 = (const float*)d_in[3];
    const float* b_hh0 = (const float*)d_in[4];
    const float* W_ih1 = (const float*)d_in[5];
    const float* W_hh1 = (const float*)d_in[6];
    const float* b_ih1 = (const float*)d_in[7];
    const float* b_hh1 = (const float*)d_in[8];
    const float* W_fc  = (const float*)d_in[9];
    const float* b_fc  = (const float*)d_in[10];

    rnn_tri5<<<dim3(NB), dim3(192), 0, stream>>>(
        x, W_ih0, W_hh0, b_ih0, b_hh0,
        W_ih1, W_hh1, b_ih1, b_hh1, W_fc, b_fc,
        (float*)d_out);
}

// Round 20
// 711.998 us; speedup vs baseline: 2.7576x; 1.0832x over previous
//
#include <hip/hip_runtime.h>

#define NI 8
#define NH 64
#define NO 8
#define NB 256
#define NT 2048

typedef float v2f __attribute__((ext_vector_type(2)));

__device__ __forceinline__ v2f fma2(v2f a, v2f b, v2f c) {
    return __builtin_elementwise_fma(a, b, c);
}

// tanh(s) = 1 - 2/(exp(2s)+1); safe at +-inf
__device__ __forceinline__ float tanh_fast(float s) {
    float e = __expf(2.0f * s);
    return fmaf(-2.0f, __builtin_amdgcn_rcpf(e + 1.0f), 1.0f);
}

// FINAL: byte-identical restore of the Round-15 kernel (measured 709.5us,
// best of 19 rounds; 2.8x over the first working kernel).
// Structure: 3-wave merged conveyor, zero barriers, busy-spin flags.
//   A: h0[t]=tanh(Whh0@h0[t-1]+u[t]); same gather -> Wih1 dot = pi[t-1]
//   C: h1[t]=tanh(pi[t]+b1+Whh1@h1[t-1]); same gather -> complete FC(t-1)/lane
//   D: u[t]=Wih0@x[t]+b0 in 8-step windows, 2-window global-load lookahead
// Techniques: amdgpu_waves_per_eu(1,1) (512-VGPR budget; weights resident),
// b128 broadcast gathers + v_pk_fma_f32, ring reads prefetched +1 step,
// deferred pi write (publish drain ~free), 32-deep rings (jitter margin).
// Bound: 2048 strictly-serial steps x ~858cyc conveyor period. HBM 0.5%,
// VALU 22%, Mfma 0 — serial-dependency-latency-bound, not a HW roofline.
__attribute__((amdgpu_waves_per_eu(1, 1)))
__global__ void __launch_bounds__(192) rnn_tri4(
    const float* __restrict__ x,
    const float* __restrict__ W_ih0, const float* __restrict__ W_hh0,
    const float* __restrict__ b_ih0, const float* __restrict__ b_hh0,
    const float* __restrict__ W_ih1, const float* __restrict__ W_hh1,
    const float* __restrict__ b_ih1, const float* __restrict__ b_hh1,
    const float* __restrict__ W_fc,  const float* __restrict__ b_fc,
    float* __restrict__ out)
{
    const int b    = blockIdx.x;
    const int tid  = threadIdx.x;
    const int wid  = tid >> 6;
    const int lane = tid & 63;

    __shared__ __align__(16) float ur[32][NH];    // D -> A ring
    __shared__ __align__(16) float pir[32][NH];   // A -> C ring
    __shared__ __align__(16) float h0s[NH];       // A-private gather buffer
    __shared__ __align__(16) float h1s[NH];       // C-private gather buffer
    __shared__ int fa, fc2, fu;

    if (tid == 0) { fa = -1; fc2 = -1; fu = -1; }
    __syncthreads();

    volatile int* vfa  = &fa;
    volatile int* vfc2 = &fc2;
    volatile int* vfu  = &fu;

    const float*  xb   = x   + (size_t)b * NT * NI;
    float*        outb = out + (size_t)b * NT * NO;
    const size_t  hid  = (size_t)NB * NT * NO;

    if (wid == 0) {
        // ========== wave A: h0 chain + pi production ==========
        v2f wh[NH / 2], wi[NH / 2];
        #pragma unroll
        for (int k = 0; k < NH / 2; ++k) {
            wh[k] = v2f{W_hh0[lane * NH + 2 * k], W_hh0[lane * NH + 2 * k + 1]};
            wi[k] = v2f{W_ih1[lane * NH + 2 * k], W_ih1[lane * NH + 2 * k + 1]};
        }
        float h0n = 0.0f, dI_prev = 0.0f;

        while (*vfu < 7) {}                      // u[0] ready (D's first window)
        asm volatile("" ::: "memory");
        float uv_next = ur[0][lane];

        for (int t = 0; t < NT; ++t) {
            if ((t & 7) == 0) {
                const int needU = (t + 8 < NT) ? t + 8 : NT - 1;
                while (*vfu < needU) {}          // u availability (covers prefetch)
                while (*vfc2 < t - 27) {}        // pir slot reuse vs C (32-ring)
                asm volatile("" ::: "memory");
            }
            h0s[lane] = h0n;                     // h0[t-1]
            const float4* hp = (const float4*)h0s;
            float4 gv[16];
            #pragma unroll
            for (int k = 0; k < 16; ++k) gv[k] = hp[k];      // issue gather
            if (t >= 2) pir[(t - 2) & 31][lane] = dI_prev;   // deferred pi write
            const float uv_cur = uv_next;
            uv_next = ur[(t + 1) & 31][lane];                // prefetch u[t+1]

            v2f aW0 = {0,0}, aW1 = {0,0}, aW2 = {0,0}, aW3 = {0,0};
            v2f aI0 = {0,0}, aI1 = {0,0}, aI2 = {0,0}, aI3 = {0,0};
            #pragma unroll
            for (int k = 0; k < 16; ++k) {
                const v2f lo = {gv[k].x, gv[k].y}, hi = {gv[k].z, gv[k].w};
                if (k & 1) {
                    aW2 = fma2(lo, wh[2 * k], aW2); aW3 = fma2(hi, wh[2 * k + 1], aW3);
                    aI2 = fma2(lo, wi[2 * k], aI2); aI3 = fma2(hi, wi[2 * k + 1], aI3);
                } else {
                    aW0 = fma2(lo, wh[2 * k], aW0); aW1 = fma2(hi, wh[2 * k + 1], aW1);
                    aI0 = fma2(lo, wi[2 * k], aI0); aI1 = fma2(hi, wi[2 * k + 1], aI1);
                }
            }
            if (t & 1) {                         // publish: all DS long returned
                asm volatile("s_waitcnt lgkmcnt(0)" ::: "memory");
                *vfa = t - 2;
            }
            const v2f sW = (aW0 + aW1) + (aW2 + aW3);
            const v2f sI = (aI0 + aI1) + (aI2 + aI3);
            dI_prev = sI.x + sI.y;               // pi[t-1], written next step
            h0n = tanh_fast(sW.x + sW.y + uv_cur);
        }

        // epilogue: pi[NT-2] (pending) and pi[NT-1] (fresh gather)
        while (*vfc2 < NT - 33) {}
        asm volatile("" ::: "memory");
        pir[(NT - 2) & 31][lane] = dI_prev;
        h0s[lane] = h0n;
        {
            const float4* hp = (const float4*)h0s;
            v2f aI0 = {0,0}, aI1 = {0,0}, aI2 = {0,0}, aI3 = {0,0};
            #pragma unroll
            for (int k = 0; k < 16; ++k) {
                const float4 g = hp[k];
                const v2f lo = {g.x, g.y}, hi = {g.z, g.w};
                if (k & 1) { aI2 = fma2(lo, wi[2 * k], aI2); aI3 = fma2(hi, wi[2 * k + 1], aI3); }
                else       { aI0 = fma2(lo, wi[2 * k], aI0); aI1 = fma2(hi, wi[2 * k + 1], aI1); }
            }
            const v2f sI = (aI0 + aI1) + (aI2 + aI3);
            pir[(NT - 1) & 31][lane] = sI.x + sI.y;
        }
        asm volatile("s_waitcnt lgkmcnt(0)" ::: "memory");
        *vfa = NT - 1;
        out[hid + (size_t)b * NH + lane] = h0n;                     // h0 final
    } else if (wid == 1) {
        // ========== wave C: h1 chain + FC ==========
        const int o = lane & 7;
        v2f wh1[NH / 2], wf[NH / 2];
        #pragma unroll
        for (int k = 0; k < NH / 2; ++k) {
            wh1[k] = v2f{W_hh1[lane * NH + 2 * k], W_hh1[lane * NH + 2 * k + 1]};
            wf[k]  = v2f{W_fc[o * NH + 2 * k],     W_fc[o * NH + 2 * k + 1]};
        }
        const float bias1 = b_ih1[lane] + b_hh1[lane];
        const float bfc   = b_fc[o];
        float h1n = 0.0f;

        while (*vfa < 1) {}                      // pi[0] ready
        asm volatile("" ::: "memory");
        float pv_next = pir[0][lane];

        for (int t = 0; t < NT; ++t) {
            if ((t & 3) == 0) {                  // covers prefetch through t+4
                const int need = (t + 4 < NT) ? t + 4 : NT - 1;
                while (*vfa < need) {}
                asm volatile("" ::: "memory");
            }
            h1s[lane] = h1n;                     // h1[t-1]
            const float4* hp = (const float4*)h1s;
            float4 gv[16];
            #pragma unroll
            for (int k = 0; k < 16; ++k) gv[k] = hp[k];
            const float pv_cur = pv_next;
            pv_next = pir[(t + 1) & 31][lane];   // prefetch pi[t+1]

            // on-chain dot first: Whh1 @ h1[t-1]
            v2f aW0 = {0,0}, aW1 = {0,0}, aW2 = {0,0}, aW3 = {0,0};
            #pragma unroll
            for (int k = 0; k < 16; ++k) {
                const v2f lo = {gv[k].x, gv[k].y}, hi = {gv[k].z, gv[k].w};
                if (k & 1) { aW2 = fma2(lo, wh1[2 * k], aW2); aW3 = fma2(hi, wh1[2 * k + 1], aW3); }
                else       { aW0 = fma2(lo, wh1[2 * k], aW0); aW1 = fma2(hi, wh1[2 * k + 1], aW1); }
            }
            const v2f sW = (aW0 + aW1) + (aW2 + aW3);
            h1n = tanh_fast(sW.x + sW.y + pv_cur + bias1);

            // off-chain: FC(t-1) from the same gather (complete dot per lane)
            v2f aF0 = {0,0}, aF1 = {0,0}, aF2 = {0,0}, aF3 = {0,0};
            #pragma unroll
            for (int k = 0; k < 16; ++k) {
                const v2f lo = {gv[k].x, gv[k].y}, hi = {gv[k].z, gv[k].w};
                if (k & 1) { aF2 = fma2(lo, wf[2 * k], aF2); aF3 = fma2(hi, wf[2 * k + 1], aF3); }
                else       { aF0 = fma2(lo, wf[2 * k], aF0); aF1 = fma2(hi, wf[2 * k + 1], aF1); }
            }
            const v2f sF = (aF0 + aF1) + (aF2 + aF3);
            if (t > 0 && lane < NO)
                outb[(size_t)(t - 1) * NO + o] = sF.x + sF.y + bfc;  // fire-and-forget

            if ((t & 3) == 3) {                  // consumption progress
                asm volatile("s_waitcnt lgkmcnt(0)" ::: "memory");
                *vfc2 = t;
            }
        }

        // epilogue: FC(NT-1)
        h1s[lane] = h1n;
        {
            const float4* hp = (const float4*)h1s;
            v2f aF0 = {0,0}, aF1 = {0,0}, aF2 = {0,0}, aF3 = {0,0};
            #pragma unroll
            for (int k = 0; k < 16; ++k) {
                const float4 g = hp[k];
                const v2f lo = {g.x, g.y}, hi = {g.z, g.w};
                if (k & 1) { aF2 = fma2(lo, wf[2 * k], aF2); aF3 = fma2(hi, wf[2 * k + 1], aF3); }
                else       { aF0 = fma2(lo, wf[2 * k], aF0); aF1 = fma2(hi, wf[2 * k + 1], aF1); }
            }
            const v2f sF = (aF0 + aF1) + (aF2 + aF3);
            if (lane < NO) outb[(size_t)(NT - 1) * NO + o] = sF.x + sF.y + bfc;
        }
        out[hid + (size_t)NB * NH + (size_t)b * NH + lane] = h1n;   // h1 final
    } else if (wid == 2) {
        // ========== wave D: u producer, 8-step windows, 2-window lookahead ==========
        float wih0r[NI];
        #pragma unroll
        for (int i = 0; i < NI; ++i) wih0r[i] = W_ih0[lane * NI + i];
        const float bias0 = b_ih0[lane] + b_hh0[lane];

        float4 xc[16], xn[16];                   // xc = window w, xn = window w+1
        #pragma unroll
        for (int j = 0; j < 8; ++j) {
            xc[2 * j]     = *(const float4*)(xb + (size_t)j * NI);
            xc[2 * j + 1] = *(const float4*)(xb + (size_t)j * NI + 4);
        }
        #pragma unroll
        for (int j = 0; j < 8; ++j) {
            xn[2 * j]     = *(const float4*)(xb + (size_t)(8 + j) * NI);
            xn[2 * j + 1] = *(const float4*)(xb + (size_t)(8 + j) * NI + 4);
        }

        for (int w = 0; w < NT / 8; ++w) {
            while (*vfa < 8 * w - 20) {}         // ur slot reuse vs A (margin 14)
            asm volatile("" ::: "memory");
            #pragma unroll
            for (int j = 0; j < 8; ++j) {
                float u = bias0;
                u = fmaf(xc[2 * j].x,     wih0r[0], u);
                u = fmaf(xc[2 * j].y,     wih0r[1], u);
                u = fmaf(xc[2 * j].z,     wih0r[2], u);
                u = fmaf(xc[2 * j].w,     wih0r[3], u);
                u = fmaf(xc[2 * j + 1].x, wih0r[4], u);
                u = fmaf(xc[2 * j + 1].y, wih0r[5], u);
                u = fmaf(xc[2 * j + 1].z, wih0r[6], u);
                u = fmaf(xc[2 * j + 1].w, wih0r[7], u);
                ur[(8 * w + j) & 31][lane] = u;
            }
            asm volatile("s_waitcnt lgkmcnt(0)" ::: "memory");
            *vfu = 8 * w + 7;
            #pragma unroll
            for (int j = 0; j < 16; ++j) xc[j] = xn[j];      // rotate windows
            if (w + 2 < NT / 8) {                // load window w+2 (used in 2 windows)
                const size_t base = (size_t)(w + 2) * 8;
                #pragma unroll
                for (int j = 0; j < 8; ++j) {
                    xn[2 * j]     = *(const float4*)(xb + (base + j) * NI);
                    xn[2 * j + 1] = *(const float4*)(xb + (base + j) * NI + 4);
                }
            }
        }
    }
}

extern "C" void kernel_launch(void* const* d_in, const int* in_sizes, int n_in,
                              void* d_out, int out_size, void* d_ws, size_t ws_size,
                              hipStream_t stream) {
    const float* x     = (const float*)d_in[0];
    const float* W_ih0 = (const float*)d_in[1];
    const float* W_hh0 = (const float*)d_in[2];
    const float* b_ih0 = (const float*)d_in[3];
    const float* b_hh0 = (const float*)d_in[4];
    const float* W_ih1 = (const float*)d_in[5];
    const float* W_hh1 = (const float*)d_in[6];
    const float* b_ih1 = (const float*)d_in[7];
    const float* b_hh1 = (const float*)d_in[8];
    const float* W_fc  = (const float*)d_in[9];
    const float* b_fc  = (const float*)d_in[10];

    rnn_tri4<<<dim3(NB), dim3(192), 0, stream>>>(
        x, W_ih0, W_hh0, b_ih0, b_hh0,
        W_ih1, W_hh1, b_ih1, b_hh1, W_fc, b_fc,
        (float*)d_out);
}